// Round 7
// baseline (450.811 us; speedup 1.0000x reference)
//
#include <hip/hip_runtime.h>
#include <math.h>

#define KC 24
constexpr int D = 16;
constexpr int B = 4;
constexpr int N = 512 * 1024;          // points per image, 2^19
constexpr float DELTA_VAR = 1.0f;
constexpr float DELTA_DIST = 2.0f;

constexpr int REP = 8;                 // LDS bin replicas (replica = lane&7)
constexpr int RS  = KC * 17;           // 408
constexpr int CS  = 33;
constexpr int TPB = 256;               // 4 waves
constexpr int GRID = 512;              // 2 blocks/CU guaranteed at <=256 VGPR
constexpr int GPT = 4;                 // groups of 4 pts per thread -> 16 pts/thread
constexpr int GSTRIDE = TPB * 4;       // 1024 points between a thread's groups
constexpr int BPTS = TPB * GPT * 4;    // 4096 points per block; 128 blocks per image

// ws (floats): g_sums [1536] | g_cnt [96] | g_varp [64] | g_bar [1 int]

__device__ inline unsigned pk_bf16(float a, float b) {  // RNE pack (a=low, b=high)
    unsigned ua = __float_as_uint(a), ub = __float_as_uint(b);
    ua += 0x7fffu + ((ua >> 16) & 1u);
    ub += 0x7fffu + ((ub >> 16) & 1u);
    return (ua >> 16) | (ub & 0xffff0000u);
}
__device__ inline float lo_bf16(unsigned u) { return __uint_as_float(u << 16); }
__device__ inline float hi_bf16(unsigned u) { return __uint_as_float(u & 0xffff0000u); }

// ------- Fused: sums -> grid barrier -> hinged variance; data read ONCE, stash in VGPRs -------
// launch_bounds(256,2): 8 waves/CU -> 2 waves/SIMD -> 256-VGPR cap under BOTH the
// waves-per-EU and blocks-per-CU readings of the 2nd arg. Need ~190 regs -> no spill.
__global__ __launch_bounds__(TPB, 2) void k_fused(const float* __restrict__ data,
                                                  const int* __restrict__ labels,
                                                  float* __restrict__ g_sums,
                                                  float* __restrict__ g_cnt,
                                                  float* __restrict__ g_varp,
                                                  int* __restrict__ g_bar) {
    __shared__ float s_sum[REP * RS];     // 13 KB
    __shared__ float s_cnt[REP * CS];
    __shared__ float s_c[KC * 20];        // centers, b128-readable rows
    __shared__ float s_ic[KC];            // 1/count
    __shared__ float s_part[TPB / 64];
    const int t = threadIdx.x;
    for (int i = t; i < REP * RS; i += TPB) s_sum[i] = 0.f;
    for (int i = t; i < REP * CS; i += TPB) s_cnt[i] = 0.f;
    __syncthreads();

    const int base = blockIdx.x * BPTS;   // block's 4096 consecutive points, one image
    const int b    = base >> 19;
    const int n0   = (base & (N - 1)) + t * 4;

    int4 lab[GPT];
#pragma unroll
    for (int g = 0; g < GPT; ++g)
        lab[g] = *(const int4*)(labels + base + g * GSTRIDE + t * 4);

    const int rb = (t & 7) * RS;
    unsigned u[GPT][D][2];                // bf16x2 stash: 128 VGPRs

    const float* dp0 = data + (size_t)(b * D) * N + n0;
#pragma unroll
    for (int d = 0; d < D; ++d) {
        float4 v[GPT];
#pragma unroll
        for (int g = 0; g < GPT; ++g)     // 4 coalesced 16B loads in flight
            v[g] = *(const float4*)(dp0 + (size_t)d * N + g * GSTRIDE);
#pragma unroll
        for (int g = 0; g < GPT; ++g) {
            atomicAdd(&s_sum[rb + lab[g].x * 17 + d], v[g].x);
            atomicAdd(&s_sum[rb + lab[g].y * 17 + d], v[g].y);
            atomicAdd(&s_sum[rb + lab[g].z * 17 + d], v[g].z);
            atomicAdd(&s_sum[rb + lab[g].w * 17 + d], v[g].w);
            u[g][d][0] = pk_bf16(v[g].x, v[g].y);
            u[g][d][1] = pk_bf16(v[g].z, v[g].w);
        }
    }
    {
        const int cb = (t & 7) * CS;
#pragma unroll
        for (int g = 0; g < GPT; ++g) {
            atomicAdd(&s_cnt[cb + lab[g].x], 1.f);
            atomicAdd(&s_cnt[cb + lab[g].y], 1.f);
            atomicAdd(&s_cnt[cb + lab[g].z], 1.f);
            atomicAdd(&s_cnt[cb + lab[g].w], 1.f);
        }
    }
    __syncthreads();

    // block partials -> global (device-scope atomics); strided: KC*D=384 > TPB
    for (int i = t; i < KC * D; i += TPB) {
        float s = 0.f;
#pragma unroll
        for (int r = 0; r < REP; ++r) s += s_sum[r * RS + (i >> 4) * 17 + (i & 15)];
        atomicAdd(&g_sums[b * (KC * D) + i], s);
    }
    if (t < KC) {
        float s = 0.f;
#pragma unroll
        for (int r = 0; r < REP; ++r) s += s_cnt[r * CS + t];
        atomicAdd(&g_cnt[b * KC + t], s);
    }

    // ---- grid-wide barrier (all 512 blocks co-resident: 2/CU at <=256 VGPR) ----
    __threadfence();
    __syncthreads();
    if (t == 0) {
        __hip_atomic_fetch_add(g_bar, 1, __ATOMIC_ACQ_REL, __HIP_MEMORY_SCOPE_AGENT);
        while (__hip_atomic_load(g_bar, __ATOMIC_ACQUIRE, __HIP_MEMORY_SCOPE_AGENT) < GRID)
            __builtin_amdgcn_s_sleep(2);
    }
    __syncthreads();

    // centers (agent-scope loads: coherent across XCDs)
    if (t < KC)
        s_ic[t] = 1.0f / __hip_atomic_load(&g_cnt[b * KC + t],
                                           __ATOMIC_RELAXED, __HIP_MEMORY_SCOPE_AGENT);
    __syncthreads();
    for (int i = t; i < KC * D; i += TPB) {
        float s = __hip_atomic_load(&g_sums[b * (KC * D) + i],
                                    __ATOMIC_RELAXED, __HIP_MEMORY_SCOPE_AGENT);
        s_c[(i >> 4) * 20 + (i & 15)] = s * s_ic[i >> 4];
    }
    __syncthreads();

    // ---- phase 2: hinge from register-held bf16; var = sum h^2 / cnt[lab] ----
    float hsum = 0.f;
#define PT(LAB, G, R, HALF) do {                                              \
        const float* cp = &s_c[(LAB) * 20];                                   \
        float q = 0.f;                                                        \
        _Pragma("unroll")                                                     \
        for (int d4 = 0; d4 < 4; ++d4) {                                      \
            float4 cv = *(const float4*)(cp + 4 * d4);                        \
            float x, df;                                                      \
            x = (HALF) ? hi_bf16(u[G][4*d4+0][R]) : lo_bf16(u[G][4*d4+0][R]); \
            df = x - cv.x; q += df * df;                                      \
            x = (HALF) ? hi_bf16(u[G][4*d4+1][R]) : lo_bf16(u[G][4*d4+1][R]); \
            df = x - cv.y; q += df * df;                                      \
            x = (HALF) ? hi_bf16(u[G][4*d4+2][R]) : lo_bf16(u[G][4*d4+2][R]); \
            df = x - cv.z; q += df * df;                                      \
            x = (HALF) ? hi_bf16(u[G][4*d4+3][R]) : lo_bf16(u[G][4*d4+3][R]); \
            df = x - cv.w; q += df * df;                                      \
        }                                                                     \
        float h = fmaxf(sqrtf(q) - DELTA_VAR, 0.f);                           \
        hsum += h * h * s_ic[LAB];                                            \
    } while (0)

#pragma unroll
    for (int g = 0; g < GPT; ++g) {
        PT(lab[g].x, g, 0, 0);
        PT(lab[g].y, g, 0, 1);
        PT(lab[g].z, g, 1, 0);
        PT(lab[g].w, g, 1, 1);
    }
#undef PT

    for (int o = 32; o > 0; o >>= 1) hsum += __shfl_down(hsum, o, 64);
    if ((t & 63) == 0) s_part[t >> 6] = hsum;
    __syncthreads();
    if (t == 0) {
        float s = 0.f;
#pragma unroll
        for (int w = 0; w < TPB / 64; ++w) s += s_part[w];
        atomicAdd(&g_varp[blockIdx.x & 63], s);
    }
}

// ---------------- Finalize ----------------
__global__ __launch_bounds__(128) void k_final(const float* __restrict__ g_sums,
                                               const float* __restrict__ g_cnt,
                                               const float* __restrict__ g_varp,
                                               float* __restrict__ out) {
    __shared__ float s_c[B * KC * 17];
    __shared__ float s_red[2];
    const int t = threadIdx.x;

    float acc = 0.f;
    if (t < B * KC) {
        float cnt = g_cnt[t];
        float ns = 0.f;
        for (int d = 0; d < D; ++d) {
            float c = g_sums[t * D + d] / cnt;
            s_c[t * 17 + d] = c;
            ns += c * c;
        }
        acc = sqrtf(ns) / (float)KC;     // reg term
    }
    if (t < 64) acc += g_varp[t];        // var term partials
    __syncthreads();

    float dacc = 0.f;  // raw sum over [B,K,K] incl. diagonal (= delta_dist^2 each)
    for (int idx = t; idx < B * KC * KC; idx += 128) {
        int b = idx / (KC * KC);
        int r = idx % (KC * KC);
        int i = r / KC, j = r % KC;
        float hd;
        if (i == j) {
            hd = DELTA_DIST * DELTA_DIST;
        } else {
            const float* ci = &s_c[(b * KC + i) * 17];
            const float* cj = &s_c[(b * KC + j) * 17];
            float sq = 0.f;
            for (int d = 0; d < D; ++d) { float df = ci[d] - cj[d]; sq += df * df; }
            float hh = fmaxf(DELTA_DIST - sqrtf(sq), 0.f);
            hd = hh * hh;
        }
        dacc += hd;
    }
    float total = acc + dacc / (2.f * KC * (KC - 1));

    for (int o = 32; o > 0; o >>= 1) total += __shfl_down(total, o, 64);
    if ((t & 63) == 0) s_red[t >> 6] = total;
    __syncthreads();
    if (t == 0) out[0] = (s_red[0] + s_red[1]) / (float)B;
}

extern "C" void kernel_launch(void* const* d_in, const int* in_sizes, int n_in,
                              void* d_out, int out_size, void* d_ws, size_t ws_size,
                              hipStream_t stream) {
    const float* data  = (const float*)d_in[0];
    const int* labels  = (const int*)d_in[1];
    float* ws = (float*)d_ws;
    float* g_sums = ws;                    // 1536
    float* g_cnt  = ws + B * KC * D;       // 96
    float* g_varp = g_cnt + B * KC;        // 64
    int*   g_bar  = (int*)(g_varp + 64);   // 1

    hipMemsetAsync(d_ws, 0, (B * KC * D + B * KC + 64 + 4) * sizeof(float), stream);

    k_fused<<<GRID, TPB, 0, stream>>>(data, labels, g_sums, g_cnt, g_varp, g_bar);
    k_final<<<1, 128, 0, stream>>>(g_sums, g_cnt, g_varp, (float*)d_out);
}